// Round 6
// baseline (297.475 us; speedup 1.0000x reference)
//
#include <hip/hip_runtime.h>
#include <math.h>

#define Bd 2
#define Sd 2048
#define Ed 1024
#define Hd 16
#define Dd 64
#define Md (Bd * Sd)     // 4096
#define Kd 1024          // GEMM K == E
#define Nd 1024          // GEMM N == E

typedef __attribute__((ext_vector_type(8))) short bf16x8;
typedef __attribute__((ext_vector_type(4))) float f32x4;

__device__ __forceinline__ unsigned short f2bf(float f) {
    unsigned x = __float_as_uint(f);
    x += 0x7fffu + ((x >> 16) & 1u);
    return (unsigned short)(x >> 16);
}

__device__ __forceinline__ void gl2lds16(const unsigned short* g, unsigned short* l) {
    // 16B-per-lane async global->LDS (global_load_lds_dwordx4).
    // LDS dest = wave-uniform base + lane*16B; global addr is per-lane.
    __builtin_amdgcn_global_load_lds(
        (__attribute__((address_space(1))) void*)g,
        (__attribute__((address_space(3))) void*)l, 16, 0, 0);
}

__device__ __forceinline__ void cvt_store8(const float4& x, const float4& y,
                                           unsigned short* dst) {
    ushort4 lo = make_ushort4(f2bf(x.x), f2bf(x.y), f2bf(x.z), f2bf(x.w));
    ushort4 hi = make_ushort4(f2bf(y.x), f2bf(y.y), f2bf(y.z), f2bf(y.w));
    *(ushort4*)dst = lo;
    *(ushort4*)(dst + 4) = hi;
}

// ---------------------------------------------------------------------------
// Fused weight transpose+convert: W[K,N] fp32 -> Wt[N,K] bf16 (grid.z = 4)
// ---------------------------------------------------------------------------
__global__ __launch_bounds__(256) void wtrans_k(
    const float* __restrict__ w0, const float* __restrict__ w1,
    const float* __restrict__ w2, const float* __restrict__ w3,
    unsigned short* __restrict__ o0, unsigned short* __restrict__ o1,
    unsigned short* __restrict__ o2, unsigned short* __restrict__ o3)
{
    __shared__ unsigned short Tl[32][36];
    const int z = blockIdx.z;
    const float* W = z == 0 ? w0 : z == 1 ? w1 : z == 2 ? w2 : w3;
    unsigned short* Wt = z == 0 ? o0 : z == 1 ? o1 : z == 2 ? o2 : o3;

    const int t = threadIdx.x;
    const int r = t >> 3;
    const int c4 = (t & 7) * 4;
    const int k0 = blockIdx.y * 32;
    const int n0 = blockIdx.x * 32;

    float4 v = *(const float4*)(W + (size_t)(k0 + r) * Nd + n0 + c4);
    Tl[c4 + 0][r] = f2bf(v.x);
    Tl[c4 + 1][r] = f2bf(v.y);
    Tl[c4 + 2][r] = f2bf(v.z);
    Tl[c4 + 3][r] = f2bf(v.w);
    __syncthreads();
    ushort4 u = make_ushort4(Tl[r][c4 + 0], Tl[r][c4 + 1], Tl[r][c4 + 2], Tl[r][c4 + 3]);
    *(ushort4*)(Wt + (size_t)(n0 + r) * Kd + k0 + c4) = u;
}

// ---------------------------------------------------------------------------
// bf16 MFMA GEMM v2: C = A @ Bt^T (+bias)*oscale.  128x128 tile, BK=32.
// Round-6 pipeline (pattern proven in attn r5): double-buffered LDS, ONE
// barrier per K-iter; prefetch of iter k+1 issues right after the barrier
// and flies during the MFMAs; the next barrier's vmcnt/lgkm drain syncs it.
// AF32=true: A is fp32 — staged via VGPR (global_load_dwordx4 -> cvt ->
// ds_write_b128 at END of iter body, so load latency hides under MFMA).
// This fuses the former cvt3 kernel into the GEMM for free.
// AF32=false: A is bf16, staged via global_load_lds like B.
// mode 0: fp32 flat [M,N];  mode 1: bf16 [B,H,S,D];  mode 2: bf16 [B,H,D,S]
// ---------------------------------------------------------------------------
template <bool AF32>
__device__ __forceinline__ void gemm_v2(
    const void* __restrict__ Ap, const unsigned short* __restrict__ Bt,
    const float* __restrict__ bias, void* __restrict__ Yv, int mode, float oscale)
{
    __shared__ unsigned short As[2][128 * 32];
    __shared__ unsigned short Bs[2][128 * 32];

    const int tid  = threadIdx.x;
    const int w    = tid >> 6;
    const int lane = tid & 63;
    const int ln   = lane & 15;
    const int quad = lane >> 4;
    const int m0 = blockIdx.y * 128;
    const int n0 = blockIdx.x * 128;
    const int wm = (w >> 1) * 64;
    const int wn = (w & 1) * 64;

    // staging: 8 segments of 16 rows x 32 cols; wave w owns segs {2w, 2w+1}.
    // lane covers (row lane>>2, 8 cols at (lane&3)*8) — matches the lane*16B
    // scatter of global_load_lds, and ds_write_b128 is 8-round conflict-free.
    const int seg  = w * 2;
    const int lrow = lane >> 2;
    const int lcol = (lane & 3) * 8;
    const int aoff = seg * 512 + lrow * 32 + lcol;   // LDS element offset

    const unsigned short* Bg0 = Bt + (size_t)(n0 + seg * 16 + lrow) * Kd + lcol;
    const unsigned short* Bg1 = Bg0 + 16 * Kd;

    const float*          A32g0 = (const float*)Ap
                                  + (size_t)(m0 + seg * 16 + lrow) * Kd + lcol;
    const float*          A32g1 = A32g0 + 16 * Kd;
    const unsigned short* A16g0 = (const unsigned short*)Ap
                                  + (size_t)(m0 + seg * 16 + lrow) * Kd + lcol;
    const unsigned short* A16g1 = A16g0 + 16 * Kd;

    f32x4 acc[4][4];
    #pragma unroll
    for (int i = 0; i < 4; ++i)
        #pragma unroll
        for (int j = 0; j < 4; ++j)
            acc[i][j] = (f32x4){0.f, 0.f, 0.f, 0.f};

    // ---- prologue: stage iter 0 into buffer 0 ----
    gl2lds16(Bg0, &Bs[0][seg * 512]);
    gl2lds16(Bg1, &Bs[0][seg * 512 + 512]);
    if constexpr (AF32) {
        float4 a0 = *(const float4*)(A32g0);
        float4 a1 = *(const float4*)(A32g0 + 4);
        float4 b0 = *(const float4*)(A32g1);
        float4 b1 = *(const float4*)(A32g1 + 4);
        cvt_store8(a0, a1, &As[0][aoff]);
        cvt_store8(b0, b1, &As[0][aoff + 512]);
    } else {
        gl2lds16(A16g0, &As[0][seg * 512]);
        gl2lds16(A16g1, &As[0][seg * 512 + 512]);
    }

    for (int k0 = 0; k0 < Kd; k0 += 32) {
        const int buf = (k0 >> 5) & 1;
        __syncthreads();   // drains staging of buf; all reads of buf^1 done

        // ---- prefetch iter k0+32 into buf^1 (flies during compute) ----
        const bool more = (k0 + 32 < Kd);
        float4 pa0, pa1, pb0, pb1;
        if (more) {
            gl2lds16(Bg0 + k0 + 32, &Bs[buf ^ 1][seg * 512]);
            gl2lds16(Bg1 + k0 + 32, &Bs[buf ^ 1][seg * 512 + 512]);
            if constexpr (AF32) {
                pa0 = *(const float4*)(A32g0 + k0 + 32);
                pa1 = *(const float4*)(A32g0 + k0 + 36);
                pb0 = *(const float4*)(A32g1 + k0 + 32);
                pb1 = *(const float4*)(A32g1 + k0 + 36);
            } else {
                gl2lds16(A16g0 + k0 + 32, &As[buf ^ 1][seg * 512]);
                gl2lds16(A16g1 + k0 + 32, &As[buf ^ 1][seg * 512 + 512]);
            }
        }

        // ---- compute on buf ----
        bf16x8 af[4], bfr[4];
        #pragma unroll
        for (int mi = 0; mi < 4; ++mi)
            af[mi] = *(const bf16x8*)(&As[buf][(wm + mi * 16 + ln) * 32 + quad * 8]);
        #pragma unroll
        for (int ni = 0; ni < 4; ++ni)
            bfr[ni] = *(const bf16x8*)(&Bs[buf][(wn + ni * 16 + ln) * 32 + quad * 8]);
        #pragma unroll
        for (int mi = 0; mi < 4; ++mi)
            #pragma unroll
            for (int ni = 0; ni < 4; ++ni)
                acc[mi][ni] = __builtin_amdgcn_mfma_f32_16x16x32_bf16(
                    af[mi], bfr[ni], acc[mi][ni], 0, 0, 0);

        // ---- A convert+store at end: load latency hid under the MFMAs ----
        if (AF32 && more) {
            cvt_store8(pa0, pa1, &As[buf ^ 1][aoff]);
            cvt_store8(pb0, pb1, &As[buf ^ 1][aoff + 512]);
        }
    }

    // ---- epilogue.  C tile layout: row m = quad*4+reg, col n = ln ----
    float bval[4];
    #pragma unroll
    for (int ni = 0; ni < 4; ++ni) bval[ni] = bias[n0 + wn + ni * 16 + ln];

    if (mode == 0) {
        float* Y = (float*)Yv;
        #pragma unroll
        for (int mi = 0; mi < 4; ++mi) {
            #pragma unroll
            for (int ni = 0; ni < 4; ++ni) {
                int n = n0 + wn + ni * 16 + ln;
                #pragma unroll
                for (int r = 0; r < 4; ++r) {
                    int m = m0 + wm + mi * 16 + quad * 4 + r;
                    Y[(size_t)m * Nd + n] = (acc[mi][ni][r] + bval[ni]) * oscale;
                }
            }
        }
    } else if (mode == 1) {
        unsigned short* Y = (unsigned short*)Yv;
        #pragma unroll
        for (int mi = 0; mi < 4; ++mi) {
            #pragma unroll
            for (int ni = 0; ni < 4; ++ni) {
                int n = n0 + wn + ni * 16 + ln;
                int h = n >> 6, d = n & 63;
                #pragma unroll
                for (int r = 0; r < 4; ++r) {
                    int m = m0 + wm + mi * 16 + quad * 4 + r;
                    int b = m >> 11, s = m & 2047;
                    Y[(((size_t)b * Hd + h) * Sd + s) * Dd + d] =
                        f2bf((acc[mi][ni][r] + bval[ni]) * oscale);
                }
            }
        }
    } else {
        unsigned short* Y = (unsigned short*)Yv;
        #pragma unroll
        for (int mi = 0; mi < 4; ++mi) {
            int mbase = m0 + wm + mi * 16 + quad * 4;
            int b = mbase >> 11, s = mbase & 2047;
            #pragma unroll
            for (int ni = 0; ni < 4; ++ni) {
                int n = n0 + wn + ni * 16 + ln;
                int h = n >> 6, d = n & 63;
                ushort4 u = make_ushort4(
                    f2bf((acc[mi][ni][0] + bval[ni]) * oscale),
                    f2bf((acc[mi][ni][1] + bval[ni]) * oscale),
                    f2bf((acc[mi][ni][2] + bval[ni]) * oscale),
                    f2bf((acc[mi][ni][3] + bval[ni]) * oscale));
                *(ushort4*)(Y + (((size_t)b * Hd + h) * Dd + d) * Sd + s) = u;
            }
        }
    }
}

// Fused Q/K/V projection straight from fp32 inputs (cvt fused into staging).
__global__ __launch_bounds__(256) void proj_gemm_k(
    const float* A0, const float* A1, const float* A2,
    const unsigned short* B0, const unsigned short* B1, const unsigned short* B2,
    const float* b0, const float* b1, const float* b2,
    unsigned short* Y0, unsigned short* Y1, unsigned short* Y2)
{
    const int z = blockIdx.z;
    const float* A          = z == 0 ? A0 : z == 1 ? A1 : A2;
    const unsigned short* B = z == 0 ? B0 : z == 1 ? B1 : B2;
    const float* bias       = z == 0 ? b0 : z == 1 ? b1 : b2;
    unsigned short* Y       = z == 0 ? Y0 : z == 1 ? Y1 : Y2;
    gemm_v2<true>(A, B, bias, Y, z == 2 ? 2 : 1, z == 0 ? 0.125f : 1.0f);
}

__global__ __launch_bounds__(256) void out_gemm_k(
    const unsigned short* A, const unsigned short* Bt, const float* bias, float* Y)
{
    gemm_v2<false>(A, Bt, bias, Y, 0, 1.0f);
}

// ---------------------------------------------------------------------------
// Flash-style causal attention, MFMA bf16 16x16x32.  (unchanged from r5)
// Block = 4 waves sharing one 64-row q-tile; pair {qtA, 31-qtA} per block ->
// deterministic 33 kt-iterations.  K/V staged once per block via
// global_load_lds, double-buffered, one barrier per iteration.  XOR chunk
// swizzle for conflict-free b128.  Flat 33-iter loop w/ mid-loop epilogue.
// ---------------------------------------------------------------------------
__global__ __launch_bounds__(256) void attn_mfma_k(
    const unsigned short* __restrict__ Qg,   // [B,H,S,D] bf16, pre-scaled 1/8
    const unsigned short* __restrict__ Kg,   // [B,H,S,D] bf16
    const unsigned short* __restrict__ Vg,   // [B,H,D,S] bf16
    unsigned short* __restrict__ Aout)       // [B,S,E] bf16
{
    __shared__ unsigned short Ks[2][64 * 64];
    __shared__ unsigned short Vs[2][64 * 64];
    __shared__ unsigned short Pt[4][16][72];

    const int tid  = threadIdx.x;
    const int w    = tid >> 6;
    const int lane = tid & 63;
    const int ln   = lane & 15;
    const int quad = lane >> 4;
    const int bh   = blockIdx.y;
    const int b    = bh >> 4;
    const int h    = bh & 15;

    const size_t baseQK = (size_t)bh * Sd * Dd;
    const size_t baseV  = (size_t)bh * Dd * Sd;
    const f32x4 vzero = {0.f, 0.f, 0.f, 0.f};

    const int qtA = blockIdx.x;
    const int qtB = 31 - qtA;
    const int nA  = qtA + 1;

    const int sr = lane >> 3;
    const int sc = ((lane & 7) ^ sr) * 8;
    const int rb0 = w * 16, rb1 = w * 16 + 8;
    const int swl = ln & 7;
    const int c0 = ((quad    ) ^ swl) * 8;
    const int c1 = ((quad + 4) ^ swl) * 8;

    const int qrowA = qtA * 64 + w * 16;
    const int qrowB = qtB * 64 + w * 16;
    const unsigned short* qpA = Qg + baseQK + (size_t)(qrowA + ln) * Dd + 8 * quad;
    const unsigned short* qpB = Qg + baseQK + (size_t)(qrowB + ln) * Dd + 8 * quad;
    const bf16x8 qA0 = *(const bf16x8*)(qpA), qA1 = *(const bf16x8*)(qpA + 32);
    const bf16x8 qB0 = *(const bf16x8*)(qpB), qB1 = *(const bf16x8*)(qpB + 32);

    float m_run = -1e30f, l_lane = 0.f;
    f32x4 O[4];
    #pragma unroll
    for (int t = 0; t < 4; ++t) O[t] = vzero;

    gl2lds16(Kg + baseQK + (size_t)(rb0 + sr) * Dd + sc, &Ks[0][rb0 * 64]);
    gl2lds16(Kg + baseQK + (size_t)(rb1 + sr) * Dd + sc, &Ks[0][rb1 * 64]);
    gl2lds16(Vg + baseV  + (size_t)(rb0 + sr) * Sd + sc, &Vs[0][rb0 * 64]);
    gl2lds16(Vg + baseV  + (size_t)(rb1 + sr) * Sd + sc, &Vs[0][rb1 * 64]);

    for (int it = 0; it < 33; ++it) {
        const int cur = it & 1;
        __syncthreads();

        if (it + 1 < 33) {
            const int nk = ((it + 1 < nA) ? (it + 1) : (it + 1 - nA)) * 64;
            gl2lds16(Kg + baseQK + (size_t)(nk + rb0 + sr) * Dd + sc, &Ks[cur ^ 1][rb0 * 64]);
            gl2lds16(Kg + baseQK + (size_t)(nk + rb1 + sr) * Dd + sc, &Ks[cur ^ 1][rb1 * 64]);
            gl2lds16(Vg + baseV  + (size_t)(rb0 + sr) * Sd + nk + sc, &Vs[cur ^ 1][rb0 * 64]);
            gl2lds16(Vg + baseV  + (size_t)(rb1 + sr) * Sd + nk + sc, &Vs[cur ^ 1][rb1 * 64]);
        }

        const bool inA   = (it < nA);
        const int  krow  = (inA ? it : it - nA) * 64;
        const bool diag  = inA ? (it == nA - 1) : (it == 32);
        const int  qglob = (inA ? qrowA : qrowB) + ln;
        const bf16x8 qf0 = inA ? qA0 : qB0;
        const bf16x8 qf1 = inA ? qA1 : qB1;

        f32x4 S[4];
        #pragma unroll
        for (int t = 0; t < 4; ++t) {
            const int R = (t * 16 + ln) * 64;
            bf16x8 k0 = *(const bf16x8*)&Ks[cur][R + c0];
            bf16x8 k1 = *(const bf16x8*)&Ks[cur][R + c1];
            f32x4 z = __builtin_amdgcn_mfma_f32_16x16x32_bf16(k0, qf0, vzero, 0, 0, 0);
            S[t]     = __builtin_amdgcn_mfma_f32_16x16x32_bf16(k1, qf1, z,     0, 0, 0);
        }

        float tmax = -1e30f;
        #pragma unroll
        for (int t = 0; t < 4; ++t) {
            #pragma unroll
            for (int r = 0; r < 4; ++r) {
                if (diag && (krow + t * 16 + quad * 4 + r > qglob))
                    S[t][r] = -1e30f;
                tmax = fmaxf(tmax, S[t][r]);
            }
        }
        tmax = fmaxf(tmax, __shfl_xor(tmax, 16));
        tmax = fmaxf(tmax, __shfl_xor(tmax, 32));
        const float m_new = fmaxf(m_run, tmax);

        float p[16];
        float rsum = 0.f;
        #pragma unroll
        for (int t = 0; t < 4; ++t) {
            #pragma unroll
            for (int r = 0; r < 4; ++r) {
                float e = __expf(S[t][r] - m_new);
                p[t * 4 + r] = e;
                rsum += e;
            }
        }
        const float alpha = __expf(m_run - m_new);
        m_run  = m_new;
        l_lane = l_lane * alpha + rsum;
        #pragma unroll
        for (int t = 0; t < 4; ++t) {
            O[t][0] *= alpha; O[t][1] *= alpha;
            O[t][2] *= alpha; O[t][3] *= alpha;
        }

        #pragma unroll
        for (int t = 0; t < 4; ++t) {
            ushort4 u = make_ushort4(f2bf(p[t * 4 + 0]), f2bf(p[t * 4 + 1]),
                                     f2bf(p[t * 4 + 2]), f2bf(p[t * 4 + 3]));
            *(ushort4*)&Pt[w][ln][t * 16 + quad * 4] = u;
        }
        bf16x8 pf0 = *(const bf16x8*)&Pt[w][ln][8 * quad];
        bf16x8 pf1 = *(const bf16x8*)&Pt[w][ln][32 + 8 * quad];

        #pragma unroll
        for (int t = 0; t < 4; ++t) {
            const int R = (t * 16 + ln) * 64;
            bf16x8 v0 = *(const bf16x8*)&Vs[cur][R + c0];
            bf16x8 v1 = *(const bf16x8*)&Vs[cur][R + c1];
            O[t] = __builtin_amdgcn_mfma_f32_16x16x32_bf16(v0, pf0, O[t], 0, 0, 0);
            O[t] = __builtin_amdgcn_mfma_f32_16x16x32_bf16(v1, pf1, O[t], 0, 0, 0);
        }

        if (it == nA - 1) {
            float l_run = l_lane;
            l_run += __shfl_xor(l_run, 16);
            l_run += __shfl_xor(l_run, 32);
            float inv = 1.f / l_run;
            unsigned short* op =
                Aout + ((size_t)b * Sd + qrowA + ln) * Ed + h * 64 + quad * 4;
            #pragma unroll
            for (int t = 0; t < 4; ++t) {
                ushort4 u = make_ushort4(f2bf(O[t][0] * inv), f2bf(O[t][1] * inv),
                                         f2bf(O[t][2] * inv), f2bf(O[t][3] * inv));
                *(ushort4*)(op + t * 16) = u;
            }
            m_run = -1e30f; l_lane = 0.f;
            #pragma unroll
            for (int t = 0; t < 4; ++t) O[t] = vzero;
        }
    }

    float l_run = l_lane;
    l_run += __shfl_xor(l_run, 16);
    l_run += __shfl_xor(l_run, 32);
    float inv = 1.f / l_run;
    unsigned short* op = Aout + ((size_t)b * Sd + qrowB + ln) * Ed + h * 64 + quad * 4;
    #pragma unroll
    for (int t = 0; t < 4; ++t) {
        ushort4 u = make_ushort4(f2bf(O[t][0] * inv), f2bf(O[t][1] * inv),
                                 f2bf(O[t][2] * inv), f2bf(O[t][3] * inv));
        *(ushort4*)(op + t * 16) = u;
    }
}

// ---------------------------------------------------------------------------
extern "C" void kernel_launch(void* const* d_in, const int* in_sizes, int n_in,
                              void* d_out, int out_size, void* d_ws, size_t ws_size,
                              hipStream_t stream) {
    const float* q  = (const float*)d_in[0];
    const float* k  = (const float*)d_in[1];
    const float* v  = (const float*)d_in[2];
    const float* Wq = (const float*)d_in[3];
    const float* bq = (const float*)d_in[4];
    const float* Wk = (const float*)d_in[5];
    const float* bk = (const float*)d_in[6];
    const float* Wv = (const float*)d_in[7];
    const float* bv = (const float*)d_in[8];
    const float* Wo = (const float*)d_in[9];
    const float* bo = (const float*)d_in[10];

    const size_t TENS = (size_t)Bd * Sd * Ed;  // 4,194,304
    const size_t WE   = (size_t)Ed * Ed;       // 1,048,576
    unsigned short* Wqt = (unsigned short*)d_ws;   // bf16 [N,K]
    unsigned short* Wkt = Wqt + WE;
    unsigned short* Wvt = Wkt + WE;
    unsigned short* Wot = Wvt + WE;
    unsigned short* Qh  = Wot + WE;                // bf16 [B,H,S,D]
    unsigned short* Kh  = Qh + TENS;
    unsigned short* Vt  = Kh + TENS;               // bf16 [B,H,D,S]
    unsigned short* An  = Vt + TENS;               // bf16 [B,S,E]

    wtrans_k<<<dim3(32, 32, 4), 256, 0, stream>>>(Wq, Wk, Wv, Wo, Wqt, Wkt, Wvt, Wot);
    proj_gemm_k<<<dim3(Nd / 128, Md / 128, 3), 256, 0, stream>>>(
        q, k, v, Wqt, Wkt, Wvt, bq, bk, bv, Qh, Kh, Vt);
    attn_mfma_k<<<dim3(16, Bd * Hd), 256, 0, stream>>>(Qh, Kh, Vt, An);
    out_gemm_k<<<dim3(Nd / 128, Md / 128), 256, 0, stream>>>(An, Wot, bo, (float*)d_out);
}

// Round 7
// 233.404 us; speedup vs baseline: 1.2745x; 1.2745x over previous
//
#include <hip/hip_runtime.h>
#include <math.h>

#define Bd 2
#define Sd 2048
#define Ed 1024
#define Hd 16
#define Dd 64
#define Md (Bd * Sd)     // 4096
#define Kd 1024          // GEMM K == E
#define Nd 1024          // GEMM N == E

typedef __attribute__((ext_vector_type(8))) short bf16x8;
typedef __attribute__((ext_vector_type(4))) float f32x4;

__device__ __forceinline__ unsigned short f2bf(float f) {
    unsigned x = __float_as_uint(f);
    x += 0x7fffu + ((x >> 16) & 1u);
    return (unsigned short)(x >> 16);
}

__device__ __forceinline__ void gl2lds16(const unsigned short* g, unsigned short* l) {
    // 16B-per-lane async global->LDS (global_load_lds_dwordx4).
    __builtin_amdgcn_global_load_lds(
        (__attribute__((address_space(1))) void*)g,
        (__attribute__((address_space(3))) void*)l, 16, 0, 0);
}

// ---------------------------------------------------------------------------
// fp32->bf16 convert for q,k,v (grid.y selects tensor).  ~72 MB traffic.
// ---------------------------------------------------------------------------
__global__ __launch_bounds__(256) void cvt3_k(
    const float* __restrict__ a, const float* __restrict__ b, const float* __restrict__ c,
    unsigned short* __restrict__ da, unsigned short* __restrict__ db,
    unsigned short* __restrict__ dc, int n4)
{
    const float* s = blockIdx.y == 0 ? a : blockIdx.y == 1 ? b : c;
    unsigned short* d = blockIdx.y == 0 ? da : blockIdx.y == 1 ? db : dc;
    int i = blockIdx.x * blockDim.x + threadIdx.x;
    int stride = gridDim.x * blockDim.x;
    for (; i < n4; i += stride) {
        float4 v = ((const float4*)s)[i];
        ushort4 u = make_ushort4(f2bf(v.x), f2bf(v.y), f2bf(v.z), f2bf(v.w));
        ((ushort4*)d)[i] = u;
    }
}

// ---------------------------------------------------------------------------
// Fused weight transpose+convert: W[K,N] fp32 -> Wt[N,K] bf16 (grid.z = 4)
// ---------------------------------------------------------------------------
__global__ __launch_bounds__(256) void wtrans_k(
    const float* __restrict__ w0, const float* __restrict__ w1,
    const float* __restrict__ w2, const float* __restrict__ w3,
    unsigned short* __restrict__ o0, unsigned short* __restrict__ o1,
    unsigned short* __restrict__ o2, unsigned short* __restrict__ o3)
{
    __shared__ unsigned short Tl[32][36];
    const int z = blockIdx.z;
    const float* W = z == 0 ? w0 : z == 1 ? w1 : z == 2 ? w2 : w3;
    unsigned short* Wt = z == 0 ? o0 : z == 1 ? o1 : z == 2 ? o2 : o3;

    const int t = threadIdx.x;
    const int r = t >> 3;
    const int c4 = (t & 7) * 4;
    const int k0 = blockIdx.y * 32;
    const int n0 = blockIdx.x * 32;

    float4 v = *(const float4*)(W + (size_t)(k0 + r) * Nd + n0 + c4);
    Tl[c4 + 0][r] = f2bf(v.x);
    Tl[c4 + 1][r] = f2bf(v.y);
    Tl[c4 + 2][r] = f2bf(v.z);
    Tl[c4 + 3][r] = f2bf(v.w);
    __syncthreads();
    ushort4 u = make_ushort4(Tl[r][c4 + 0], Tl[r][c4 + 1], Tl[r][c4 + 2], Tl[r][c4 + 3]);
    *(ushort4*)(Wt + (size_t)(n0 + r) * Kd + k0 + c4) = u;
}

// ---------------------------------------------------------------------------
// bf16 MFMA GEMM v3: C = A @ Bt^T (+bias)*oscale.  128x128 tile, BK=32,
// double-buffered LDS, ONE barrier per K-iter (pattern proven in attn r5 —
// prefetch issues right after the barrier and flies under the MFMAs).
// A and B both bf16 [*,K] row-major, staged via global_load_lds width-16.
// Caller passes tile coords (m0,n0) — enables XCD-aware swizzle (r7: the
// r6 regression was A-tile L2-fill traffic; co-locating all n-blocks of an
// A-tile on one XCD makes A ~single-fetch chip-wide).
// mode 0: fp32 flat [M,N];  mode 1: bf16 [B,H,S,D];  mode 2: bf16 [B,H,D,S]
// ---------------------------------------------------------------------------
__device__ __forceinline__ void gemm_v3(
    const unsigned short* __restrict__ A, const unsigned short* __restrict__ Bt,
    const float* __restrict__ bias, void* __restrict__ Yv,
    int m0, int n0, int mode, float oscale)
{
    __shared__ unsigned short As[2][128 * 32];
    __shared__ unsigned short Bs[2][128 * 32];

    const int tid  = threadIdx.x;
    const int w    = tid >> 6;
    const int lane = tid & 63;
    const int ln   = lane & 15;
    const int quad = lane >> 4;
    const int wm = (w >> 1) * 64;
    const int wn = (w & 1) * 64;

    // staging: 8 segments of 16 rows x 32 cols; wave w owns segs {2w, 2w+1}
    const int seg  = w * 2;
    const int lrow = lane >> 2;
    const int lcol = (lane & 3) * 8;

    const unsigned short* Ag0 = A  + (size_t)(m0 + seg * 16 + lrow) * Kd + lcol;
    const unsigned short* Ag1 = Ag0 + 16 * Kd;
    const unsigned short* Bg0 = Bt + (size_t)(n0 + seg * 16 + lrow) * Kd + lcol;
    const unsigned short* Bg1 = Bg0 + 16 * Kd;

    f32x4 acc[4][4];
    #pragma unroll
    for (int i = 0; i < 4; ++i)
        #pragma unroll
        for (int j = 0; j < 4; ++j)
            acc[i][j] = (f32x4){0.f, 0.f, 0.f, 0.f};

    // prologue: stage iter 0 into buffer 0
    gl2lds16(Ag0, &As[0][seg * 512]);
    gl2lds16(Ag1, &As[0][seg * 512 + 512]);
    gl2lds16(Bg0, &Bs[0][seg * 512]);
    gl2lds16(Bg1, &Bs[0][seg * 512 + 512]);

    for (int k0 = 0; k0 < Kd; k0 += 32) {
        const int buf = (k0 >> 5) & 1;
        __syncthreads();   // drains staging of buf; all reads of buf^1 done

        if (k0 + 32 < Kd) {   // prefetch next iter into buf^1
            gl2lds16(Ag0 + k0 + 32, &As[buf ^ 1][seg * 512]);
            gl2lds16(Ag1 + k0 + 32, &As[buf ^ 1][seg * 512 + 512]);
            gl2lds16(Bg0 + k0 + 32, &Bs[buf ^ 1][seg * 512]);
            gl2lds16(Bg1 + k0 + 32, &Bs[buf ^ 1][seg * 512 + 512]);
        }

        bf16x8 af[4], bfr[4];
        #pragma unroll
        for (int mi = 0; mi < 4; ++mi)
            af[mi] = *(const bf16x8*)(&As[buf][(wm + mi * 16 + ln) * 32 + quad * 8]);
        #pragma unroll
        for (int ni = 0; ni < 4; ++ni)
            bfr[ni] = *(const bf16x8*)(&Bs[buf][(wn + ni * 16 + ln) * 32 + quad * 8]);
        #pragma unroll
        for (int mi = 0; mi < 4; ++mi)
            #pragma unroll
            for (int ni = 0; ni < 4; ++ni)
                acc[mi][ni] = __builtin_amdgcn_mfma_f32_16x16x32_bf16(
                    af[mi], bfr[ni], acc[mi][ni], 0, 0, 0);
    }

    // epilogue.  C tile layout: row m = quad*4+reg, col n = ln
    float bval[4];
    #pragma unroll
    for (int ni = 0; ni < 4; ++ni) bval[ni] = bias[n0 + wn + ni * 16 + ln];

    if (mode == 0) {
        float* Y = (float*)Yv;
        #pragma unroll
        for (int mi = 0; mi < 4; ++mi) {
            #pragma unroll
            for (int ni = 0; ni < 4; ++ni) {
                int n = n0 + wn + ni * 16 + ln;
                #pragma unroll
                for (int r = 0; r < 4; ++r) {
                    int m = m0 + wm + mi * 16 + quad * 4 + r;
                    Y[(size_t)m * Nd + n] = (acc[mi][ni][r] + bval[ni]) * oscale;
                }
            }
        }
    } else if (mode == 1) {
        unsigned short* Y = (unsigned short*)Yv;
        #pragma unroll
        for (int mi = 0; mi < 4; ++mi) {
            #pragma unroll
            for (int ni = 0; ni < 4; ++ni) {
                int n = n0 + wn + ni * 16 + ln;
                int h = n >> 6, d = n & 63;
                #pragma unroll
                for (int r = 0; r < 4; ++r) {
                    int m = m0 + wm + mi * 16 + quad * 4 + r;
                    int b = m >> 11, s = m & 2047;
                    Y[(((size_t)b * Hd + h) * Sd + s) * Dd + d] =
                        f2bf((acc[mi][ni][r] + bval[ni]) * oscale);
                }
            }
        }
    } else {
        unsigned short* Y = (unsigned short*)Yv;
        #pragma unroll
        for (int mi = 0; mi < 4; ++mi) {
            int mbase = m0 + wm + mi * 16 + quad * 4;
            int b = mbase >> 11, s = mbase & 2047;
            #pragma unroll
            for (int ni = 0; ni < 4; ++ni) {
                int n = n0 + wn + ni * 16 + ln;
                int h = n >> 6, d = n & 63;
                ushort4 u = make_ushort4(
                    f2bf((acc[mi][ni][0] + bval[ni]) * oscale),
                    f2bf((acc[mi][ni][1] + bval[ni]) * oscale),
                    f2bf((acc[mi][ni][2] + bval[ni]) * oscale),
                    f2bf((acc[mi][ni][3] + bval[ni]) * oscale));
                *(ushort4*)(Y + (((size_t)b * Hd + h) * Dd + d) * Sd + s) = u;
            }
        }
    }
}

// Fused Q/K/V projection.  Flat 768-block grid with XCD-aware decode:
// xcd = l&7 owns m-tiles {4*xcd .. 4*xcd+3}; within an XCD, n varies fastest
// (A-tile stays L2-hot across its 8 n-blocks), then m-sub, then tensor z
// (B(z) stays L2-hot across the 4 m-subs).
__global__ __launch_bounds__(256) void proj_gemm_k(
    const unsigned short* A0, const unsigned short* A1, const unsigned short* A2,
    const unsigned short* B0, const unsigned short* B1, const unsigned short* B2,
    const float* b0, const float* b1, const float* b2,
    unsigned short* Y0, unsigned short* Y1, unsigned short* Y2)
{
    const int l    = blockIdx.x;
    const int xcd  = l & 7;
    const int g    = l >> 3;          // 0..95
    const int n_t  = g & 7;           // n tile, fastest
    const int msub = (g >> 3) & 3;
    const int z    = g >> 5;          // 0..2
    const int m_t  = xcd * 4 + msub;  // 0..31

    const unsigned short* A = z == 0 ? A0 : z == 1 ? A1 : A2;
    const unsigned short* B = z == 0 ? B0 : z == 1 ? B1 : B2;
    const float* bias       = z == 0 ? b0 : z == 1 ? b1 : b2;
    unsigned short* Y       = z == 0 ? Y0 : z == 1 ? Y1 : Y2;
    gemm_v3(A, B, bias, Y, m_t * 128, n_t * 128,
            z == 2 ? 2 : 1, z == 0 ? 0.125f : 1.0f);
}

// Output projection, same swizzle (256 blocks: xcd owns 4 m-tiles).
__global__ __launch_bounds__(256) void out_gemm_k(
    const unsigned short* A, const unsigned short* Bt, const float* bias, float* Y)
{
    const int l    = blockIdx.x;
    const int xcd  = l & 7;
    const int g    = l >> 3;          // 0..31
    const int n_t  = g & 7;
    const int msub = g >> 3;          // 0..3
    const int m_t  = xcd * 4 + msub;
    gemm_v3(A, Bt, bias, Y, m_t * 128, n_t * 128, 0, 1.0f);
}

// ---------------------------------------------------------------------------
// Flash-style causal attention, MFMA bf16 16x16x32.  (unchanged from r5)
// ---------------------------------------------------------------------------
__global__ __launch_bounds__(256) void attn_mfma_k(
    const unsigned short* __restrict__ Qg,   // [B,H,S,D] bf16, pre-scaled 1/8
    const unsigned short* __restrict__ Kg,   // [B,H,S,D] bf16
    const unsigned short* __restrict__ Vg,   // [B,H,D,S] bf16
    unsigned short* __restrict__ Aout)       // [B,S,E] bf16
{
    __shared__ unsigned short Ks[2][64 * 64];
    __shared__ unsigned short Vs[2][64 * 64];
    __shared__ unsigned short Pt[4][16][72];

    const int tid  = threadIdx.x;
    const int w    = tid >> 6;
    const int lane = tid & 63;
    const int ln   = lane & 15;
    const int quad = lane >> 4;
    const int bh   = blockIdx.y;
    const int b    = bh >> 4;
    const int h    = bh & 15;

    const size_t baseQK = (size_t)bh * Sd * Dd;
    const size_t baseV  = (size_t)bh * Dd * Sd;
    const f32x4 vzero = {0.f, 0.f, 0.f, 0.f};

    const int qtA = blockIdx.x;
    const int qtB = 31 - qtA;
    const int nA  = qtA + 1;

    const int sr = lane >> 3;
    const int sc = ((lane & 7) ^ sr) * 8;
    const int rb0 = w * 16, rb1 = w * 16 + 8;
    const int swl = ln & 7;
    const int c0 = ((quad    ) ^ swl) * 8;
    const int c1 = ((quad + 4) ^ swl) * 8;

    const int qrowA = qtA * 64 + w * 16;
    const int qrowB = qtB * 64 + w * 16;
    const unsigned short* qpA = Qg + baseQK + (size_t)(qrowA + ln) * Dd + 8 * quad;
    const unsigned short* qpB = Qg + baseQK + (size_t)(qrowB + ln) * Dd + 8 * quad;
    const bf16x8 qA0 = *(const bf16x8*)(qpA), qA1 = *(const bf16x8*)(qpA + 32);
    const bf16x8 qB0 = *(const bf16x8*)(qpB), qB1 = *(const bf16x8*)(qpB + 32);

    float m_run = -1e30f, l_lane = 0.f;
    f32x4 O[4];
    #pragma unroll
    for (int t = 0; t < 4; ++t) O[t] = vzero;

    gl2lds16(Kg + baseQK + (size_t)(rb0 + sr) * Dd + sc, &Ks[0][rb0 * 64]);
    gl2lds16(Kg + baseQK + (size_t)(rb1 + sr) * Dd + sc, &Ks[0][rb1 * 64]);
    gl2lds16(Vg + baseV  + (size_t)(rb0 + sr) * Sd + sc, &Vs[0][rb0 * 64]);
    gl2lds16(Vg + baseV  + (size_t)(rb1 + sr) * Sd + sc, &Vs[0][rb1 * 64]);

    for (int it = 0; it < 33; ++it) {
        const int cur = it & 1;
        __syncthreads();

        if (it + 1 < 33) {
            const int nk = ((it + 1 < nA) ? (it + 1) : (it + 1 - nA)) * 64;
            gl2lds16(Kg + baseQK + (size_t)(nk + rb0 + sr) * Dd + sc, &Ks[cur ^ 1][rb0 * 64]);
            gl2lds16(Kg + baseQK + (size_t)(nk + rb1 + sr) * Dd + sc, &Ks[cur ^ 1][rb1 * 64]);
            gl2lds16(Vg + baseV  + (size_t)(rb0 + sr) * Sd + nk + sc, &Vs[cur ^ 1][rb0 * 64]);
            gl2lds16(Vg + baseV  + (size_t)(rb1 + sr) * Sd + nk + sc, &Vs[cur ^ 1][rb1 * 64]);
        }

        const bool inA   = (it < nA);
        const int  krow  = (inA ? it : it - nA) * 64;
        const bool diag  = inA ? (it == nA - 1) : (it == 32);
        const int  qglob = (inA ? qrowA : qrowB) + ln;
        const bf16x8 qf0 = inA ? qA0 : qB0;
        const bf16x8 qf1 = inA ? qA1 : qB1;

        f32x4 S[4];
        #pragma unroll
        for (int t = 0; t < 4; ++t) {
            const int R = (t * 16 + ln) * 64;
            bf16x8 k0 = *(const bf16x8*)&Ks[cur][R + c0];
            bf16x8 k1 = *(const bf16x8*)&Ks[cur][R + c1];
            f32x4 z = __builtin_amdgcn_mfma_f32_16x16x32_bf16(k0, qf0, vzero, 0, 0, 0);
            S[t]     = __builtin_amdgcn_mfma_f32_16x16x32_bf16(k1, qf1, z,     0, 0, 0);
        }

        float tmax = -1e30f;
        #pragma unroll
        for (int t = 0; t < 4; ++t) {
            #pragma unroll
            for (int r = 0; r < 4; ++r) {
                if (diag && (krow + t * 16 + quad * 4 + r > qglob))
                    S[t][r] = -1e30f;
                tmax = fmaxf(tmax, S[t][r]);
            }
        }
        tmax = fmaxf(tmax, __shfl_xor(tmax, 16));
        tmax = fmaxf(tmax, __shfl_xor(tmax, 32));
        const float m_new = fmaxf(m_run, tmax);

        float p[16];
        float rsum = 0.f;
        #pragma unroll
        for (int t = 0; t < 4; ++t) {
            #pragma unroll
            for (int r = 0; r < 4; ++r) {
                float e = __expf(S[t][r] - m_new);
                p[t * 4 + r] = e;
                rsum += e;
            }
        }
        const float alpha = __expf(m_run - m_new);
        m_run  = m_new;
        l_lane = l_lane * alpha + rsum;
        #pragma unroll
        for (int t = 0; t < 4; ++t) {
            O[t][0] *= alpha; O[t][1] *= alpha;
            O[t][2] *= alpha; O[t][3] *= alpha;
        }

        #pragma unroll
        for (int t = 0; t < 4; ++t) {
            ushort4 u = make_ushort4(f2bf(p[t * 4 + 0]), f2bf(p[t * 4 + 1]),
                                     f2bf(p[t * 4 + 2]), f2bf(p[t * 4 + 3]));
            *(ushort4*)&Pt[w][ln][t * 16 + quad * 4] = u;
        }
        bf16x8 pf0 = *(const bf16x8*)&Pt[w][ln][8 * quad];
        bf16x8 pf1 = *(const bf16x8*)&Pt[w][ln][32 + 8 * quad];

        #pragma unroll
        for (int t = 0; t < 4; ++t) {
            const int R = (t * 16 + ln) * 64;
            bf16x8 v0 = *(const bf16x8*)&Vs[cur][R + c0];
            bf16x8 v1 = *(const bf16x8*)&Vs[cur][R + c1];
            O[t] = __builtin_amdgcn_mfma_f32_16x16x32_bf16(v0, pf0, O[t], 0, 0, 0);
            O[t] = __builtin_amdgcn_mfma_f32_16x16x32_bf16(v1, pf1, O[t], 0, 0, 0);
        }

        if (it == nA - 1) {
            float l_run = l_lane;
            l_run += __shfl_xor(l_run, 16);
            l_run += __shfl_xor(l_run, 32);
            float inv = 1.f / l_run;
            unsigned short* op =
                Aout + ((size_t)b * Sd + qrowA + ln) * Ed + h * 64 + quad * 4;
            #pragma unroll
            for (int t = 0; t < 4; ++t) {
                ushort4 u = make_ushort4(f2bf(O[t][0] * inv), f2bf(O[t][1] * inv),
                                         f2bf(O[t][2] * inv), f2bf(O[t][3] * inv));
                *(ushort4*)(op + t * 16) = u;
            }
            m_run = -1e30f; l_lane = 0.f;
            #pragma unroll
            for (int t = 0; t < 4; ++t) O[t] = vzero;
        }
    }

    float l_run = l_lane;
    l_run += __shfl_xor(l_run, 16);
    l_run += __shfl_xor(l_run, 32);
    float inv = 1.f / l_run;
    unsigned short* op = Aout + ((size_t)b * Sd + qrowB + ln) * Ed + h * 64 + quad * 4;
    #pragma unroll
    for (int t = 0; t < 4; ++t) {
        ushort4 u = make_ushort4(f2bf(O[t][0] * inv), f2bf(O[t][1] * inv),
                                 f2bf(O[t][2] * inv), f2bf(O[t][3] * inv));
        *(ushort4*)(op + t * 16) = u;
    }
}

// ---------------------------------------------------------------------------
extern "C" void kernel_launch(void* const* d_in, const int* in_sizes, int n_in,
                              void* d_out, int out_size, void* d_ws, size_t ws_size,
                              hipStream_t stream) {
    const float* q  = (const float*)d_in[0];
    const float* k  = (const float*)d_in[1];
    const float* v  = (const float*)d_in[2];
    const float* Wq = (const float*)d_in[3];
    const float* bq = (const float*)d_in[4];
    const float* Wk = (const float*)d_in[5];
    const float* bk = (const float*)d_in[6];
    const float* Wv = (const float*)d_in[7];
    const float* bv = (const float*)d_in[8];
    const float* Wo = (const float*)d_in[9];
    const float* bo = (const float*)d_in[10];

    const size_t TENS = (size_t)Bd * Sd * Ed;  // 4,194,304
    const size_t WE   = (size_t)Ed * Ed;       // 1,048,576
    unsigned short* qb  = (unsigned short*)d_ws;   // bf16 [M,K]
    unsigned short* kb  = qb + TENS;
    unsigned short* vb  = kb + TENS;
    unsigned short* Wqt = vb + TENS;               // bf16 [N,K]
    unsigned short* Wkt = Wqt + WE;
    unsigned short* Wvt = Wkt + WE;
    unsigned short* Wot = Wvt + WE;
    unsigned short* Qh  = Wot + WE;                // bf16 [B,H,S,D]
    unsigned short* Kh  = Qh + TENS;
    unsigned short* Vt  = Kh + TENS;               // bf16 [B,H,D,S]
    unsigned short* An  = Vt + TENS;               // bf16 [B,S,E]

    cvt3_k<<<dim3(1024, 3), 256, 0, stream>>>(q, k, v, qb, kb, vb, (int)(TENS / 4));
    wtrans_k<<<dim3(32, 32, 4), 256, 0, stream>>>(Wq, Wk, Wv, Wo, Wqt, Wkt, Wvt, Wot);
    proj_gemm_k<<<dim3(768), 256, 0, stream>>>(
        qb, kb, vb, Wqt, Wkt, Wvt, bq, bk, bv, Qh, Kh, Vt);
    attn_mfma_k<<<dim3(16, Bd * Hd), 256, 0, stream>>>(Qh, Kh, Vt, An);
    out_gemm_k<<<dim3(256), 256, 0, stream>>>(An, Wot, bo, (float*)d_out);
}